// Round 1
// baseline (442.430 us; speedup 1.0000x reference)
//
#include <hip/hip_runtime.h>
#include <hip/hip_bf16.h>

// ---------- helpers ----------

__device__ __forceinline__ unsigned short f2bf(float f) {
    unsigned u = __float_as_uint(f);
    unsigned r = u + 0x7fffu + ((u >> 16) & 1u);
    return (unsigned short)(r >> 16);
}

typedef __bf16 bf16_t;
typedef bf16_t bf16x8 __attribute__((ext_vector_type(8)));
typedef float f32x4 __attribute__((ext_vector_type(4)));

typedef const __attribute__((address_space(1))) unsigned int* gptr_t;
typedef __attribute__((address_space(3))) unsigned int* lptr_t;

__device__ __forceinline__ void gload_lds16(const void* g, void* l) {
    __builtin_amdgcn_global_load_lds((gptr_t)g, (lptr_t)l, 16, 0, 0);
}

// ---------- kernel 1: column-wise max of |src| ----------
// each thread owns 4 consecutive columns (float4 loads), loops rows_per_block
// rows, then one atomicMax per column (uint-bits compare == float compare for >=0).
__global__ void colmax_kernel(const float* __restrict__ src, int rows, int cols,
                              unsigned int* __restrict__ dst, int rows_per_block) {
    int c = (blockIdx.x * blockDim.x + threadIdx.x) * 4;
    if (c >= cols) return;
    int r0 = blockIdx.y * rows_per_block;
    int r1 = min(r0 + rows_per_block, rows);
    float m0 = 0.f, m1 = 0.f, m2 = 0.f, m3 = 0.f;
    const float* p = src + (size_t)r0 * cols + c;
    for (int r = r0; r < r1; ++r, p += cols) {
        float4 v = *(const float4*)p;
        m0 = fmaxf(m0, fabsf(v.x));
        m1 = fmaxf(m1, fabsf(v.y));
        m2 = fmaxf(m2, fabsf(v.z));
        m3 = fmaxf(m3, fabsf(v.w));
    }
    atomicMax(dst + c + 0, __float_as_uint(m0));
    atomicMax(dst + c + 1, __float_as_uint(m1));
    atomicMax(dst + c + 2, __float_as_uint(m2));
    atomicMax(dst + c + 3, __float_as_uint(m3));
}

// ---------- kernel 2: s = sqrt(max_act / clip(max_w, EPS)) ----------
__global__ void s_kernel(const unsigned int* __restrict__ ma,
                         const unsigned int* __restrict__ mw,
                         float* __restrict__ s, int n) {
    int i = blockIdx.x * blockDim.x + threadIdx.x;
    if (i < n) {
        float a = __uint_as_float(ma[i]);
        float w = fmaxf(__uint_as_float(mw[i]), 1e-8f);
        s[i] = sqrtf(a / w);
    }
}

// ---------- kernel 3: 2:4 prune of (x/s), emit bf16(x)*mask ----------
// ranking on |x/s| in fp32 (bit-matches reference); value written is bf16 of
// UNSCALED x (the s cancels against W*s in the matmul).
__global__ void prune_kernel(const float* __restrict__ x, const float* __restrict__ s,
                             unsigned short* __restrict__ xsp, size_t ngroups, int cols) {
    size_t g = (size_t)blockIdx.x * blockDim.x + threadIdx.x;
    size_t stride = (size_t)gridDim.x * blockDim.x;
    for (; g < ngroups; g += stride) {
        size_t e = g * 4;
        int cb = (int)(e & (size_t)(cols - 1)); // cols is a power of two
        float4 v = *(const float4*)(x + e);
        float4 sv = *(const float4*)(s + cb);
        float a0 = fabsf(v.x / sv.x);
        float a1 = fabsf(v.y / sv.y);
        float a2 = fabsf(v.z / sv.z);
        float a3 = fabsf(v.w / sv.w);
        // rank_i = #elements that beat i; j beats i (i<j) iff a_j > a_i;
        // i beats j on ties (top_k keeps lower index first)
        int r0 = 0, r1 = 0, r2 = 0, r3 = 0;
        if (a1 > a0) r0++; else r1++;
        if (a2 > a0) r0++; else r2++;
        if (a3 > a0) r0++; else r3++;
        if (a2 > a1) r1++; else r2++;
        if (a3 > a1) r1++; else r3++;
        if (a3 > a2) r2++; else r3++;
        ushort4 o;
        o.x = (r0 < 2) ? f2bf(v.x) : (unsigned short)0;
        o.y = (r1 < 2) ? f2bf(v.y) : (unsigned short)0;
        o.z = (r2 < 2) ? f2bf(v.z) : (unsigned short)0;
        o.w = (r3 < 2) ? f2bf(v.w) : (unsigned short)0;
        *(ushort4*)(xsp + e) = o;
    }
}

// ---------- kernel 4: W fp32 -> bf16 ----------
__global__ void wconv_kernel(const float* __restrict__ W, unsigned short* __restrict__ Wb,
                             size_t ngroups) {
    size_t g = (size_t)blockIdx.x * blockDim.x + threadIdx.x;
    size_t stride = (size_t)gridDim.x * blockDim.x;
    for (; g < ngroups; g += stride) {
        size_t e = g * 4;
        float4 v = *(const float4*)(W + e);
        ushort4 o;
        o.x = f2bf(v.x);
        o.y = f2bf(v.y);
        o.z = f2bf(v.z);
        o.w = f2bf(v.w);
        *(ushort4*)(Wb + e) = o;
    }
}

// ---------- kernel 5: bf16 B^T GEMM (m97 structure) ----------
// C[m,n] = sum_k A[m,k] * B[n,k];  A: MxK bf16 row-major, B: NxK bf16 row-major.
// 128x128 tile, BK=32, 4 waves (2x2), 4x4 16x16x32 MFMA frags per wave,
// global_load_lds width-16 staging, single-buffered LDS, 2 barriers/K-step.
#define TILE 128
#define BK 32

__global__ __launch_bounds__(256, 2) void gemm_bt(
        const unsigned short* __restrict__ A,
        const unsigned short* __restrict__ B,
        float* __restrict__ C, int M, int N, int K) {
    __shared__ unsigned short sA[TILE * BK];
    __shared__ unsigned short sB[TILE * BK];
    const int tid = threadIdx.x;
    const int w = tid >> 6;
    const int l = tid & 63;
    const int brow = blockIdx.y * TILE;
    const int bcol = blockIdx.x * TILE;
    const int wr = w >> 1;
    const int wc = w & 1;

    f32x4 acc[4][4] = {};

    // staging geometry: chunk c (0/1) covers rows c*64 + w*16 + (l>>2),
    // cols (l&3)*8 .. +7 ; LDS dest = base + c*4096 + w*1024 (wave-uniform)
    const int rA = (l >> 2);
    const int cA = (l & 3) * 8;
    const unsigned short* gA = A + (size_t)(brow + w * 16 + rA) * K + cA;
    const unsigned short* gB = B + (size_t)(bcol + w * 16 + rA) * K + cA;
    char* lA0 = (char*)sA + w * 1024;
    char* lA1 = (char*)sA + 4096 + w * 1024;
    char* lB0 = (char*)sB + w * 1024;
    char* lB1 = (char*)sB + 4096 + w * 1024;
    const size_t rowskip = (size_t)64 * K;

    const int laneRow = l & 15;
    const int laneK = (l >> 4) * 8;

    for (int k0 = 0; k0 < K; k0 += BK) {
        gload_lds16(gA + k0, lA0);
        gload_lds16(gA + k0 + rowskip, lA1);
        gload_lds16(gB + k0, lB0);
        gload_lds16(gB + k0 + rowskip, lB1);
        __syncthreads();

        bf16x8 af[4], bfr[4];
#pragma unroll
        for (int m = 0; m < 4; ++m) {
            int off = (wr * 64 + m * 16 + laneRow) * BK + laneK;
            af[m] = *(const bf16x8*)&sA[off];
        }
#pragma unroll
        for (int n = 0; n < 4; ++n) {
            int off = (wc * 64 + n * 16 + laneRow) * BK + laneK;
            bfr[n] = *(const bf16x8*)&sB[off];
        }
#pragma unroll
        for (int m = 0; m < 4; ++m)
#pragma unroll
            for (int n = 0; n < 4; ++n)
                acc[m][n] = __builtin_amdgcn_mfma_f32_16x16x32_bf16(af[m], bfr[n], acc[m][n], 0, 0, 0);
        __syncthreads();
    }

    // epilogue: C/D layout col = lane&15, row = (lane>>4)*4 + reg
    const int er = (l >> 4) * 4;
    const int ec = l & 15;
#pragma unroll
    for (int m = 0; m < 4; ++m) {
#pragma unroll
        for (int n = 0; n < 4; ++n) {
            int row = brow + wr * 64 + m * 16 + er;
            int col = bcol + wc * 64 + n * 16 + ec;
            float* cp = C + (size_t)row * N + col;
#pragma unroll
            for (int r = 0; r < 4; ++r)
                cp[(size_t)r * N] = acc[m][n][r];
        }
    }
}

// ---------- launch ----------
extern "C" void kernel_launch(void* const* d_in, const int* in_sizes, int n_in,
                              void* d_out, int out_size, void* d_ws, size_t ws_size,
                              hipStream_t stream) {
    const float* x = (const float*)d_in[0];
    const float* W = (const float*)d_in[1];
    float* out = (float*)d_out;

    const int K = 4096;                       // inner dim (x cols / W cols)
    const int Nout = in_sizes[1] / K;         // 4096 (W rows)
    const size_t Mrows = (size_t)in_sizes[0] / K; // 8192 flattened x rows

    char* ws = (char*)d_ws;
    unsigned short* Xsp = (unsigned short*)ws;                            // M*K bf16
    unsigned short* Wb = (unsigned short*)(ws + Mrows * K * 2);           // N*K bf16
    unsigned int* ma = (unsigned int*)(ws + Mrows * K * 2 + (size_t)Nout * K * 2);
    unsigned int* mw = ma + K;
    float* s = (float*)(mw + K);

    hipMemsetAsync(ma, 0, 2 * K * sizeof(unsigned int), stream);

    dim3 blk(256);
    {
        dim3 gx(K / 1024, (unsigned)(Mrows / 64));
        colmax_kernel<<<gx, blk, 0, stream>>>(x, (int)Mrows, K, ma, 64);
        dim3 gw(K / 1024, Nout / 64);
        colmax_kernel<<<gw, blk, 0, stream>>>(W, Nout, K, mw, 64);
    }
    s_kernel<<<dim3((K + 255) / 256), blk, 0, stream>>>(ma, mw, s, K);
    {
        size_t ngroups = Mrows * K / 4;
        prune_kernel<<<dim3(2048), blk, 0, stream>>>(x, s, Xsp, ngroups, K);
        size_t wg = (size_t)Nout * K / 4;
        wconv_kernel<<<dim3(2048), blk, 0, stream>>>(W, Wb, wg);
    }
    {
        dim3 g(Nout / TILE, (unsigned)(Mrows / TILE));
        gemm_bt<<<g, dim3(256), 0, stream>>>(Xsp, Wb, out, (int)Mrows, Nout, K);
    }
}